// Round 1
// baseline (661.440 us; speedup 1.0000x reference)
//
#include <hip/hip_runtime.h>

#define B_   8192
#define NS_  16
#define NF_  16
#define D_   128
#define K_   32
#define NV_  50000
#define EPS_ 0.05f

// ws float offsets (all written by init_kernel every call)
#define WS_HF    0      // 16   h_fil
#define WS_LHF   16     // 16   log h_fil
#define WS_CCT   32     // 512  cct[k*16+j]  = sum_q hf[q]*C[q,j,k]
#define WS_CC2T  544    // 512  cc2t[k*16+j] = constC2[j,k] = sum_q hf[q]*C[q,j,k]^2
#define WS_F2    1056   // 512  f2[j*32+k]   = sum_d F[j,d,k]^2
#define WS_CT    1568   // 8192 Ct[k*256 + q*16 + j] = C[q,j,k]

__global__ __launch_bounds__(512) void init_kernel(
    const float* __restrict__ C_up, const float* __restrict__ Ff,
    const float* __restrict__ h_logits, float* __restrict__ ws)
{
    __shared__ float hf[16];
    __shared__ float Cs[16][16][32];   // Cs[q][j][k]
    const int t = threadIdx.x;

    if (t == 0) {
        float m = -3.4e38f;
        for (int p = 0; p < 16; ++p) m = fmaxf(m, h_logits[p]);
        float e[16], s = 0.f;
        for (int p = 0; p < 16; ++p) { e[p] = __expf(h_logits[p] - m); s += e[p]; }
        for (int p = 0; p < 16; ++p) {
            hf[p] = e[p] / s;
            ws[WS_HF + p]  = hf[p];
            ws[WS_LHF + p] = __logf(hf[p]);
        }
    }
    __syncthreads();

    // Build symmetric C with relu'd upper triangle, zero diag.
    for (int e = t; e < 16 * 16 * 32; e += 512) {
        int k = e & 31, j = (e >> 5) & 15, q = e >> 9;
        float v = 0.f;
        if (q < j)      { int pi = q * (31 - q) / 2 + (j - q - 1); v = fmaxf(C_up[pi * 32 + k], 0.f); }
        else if (j < q) { int pi = j * (31 - j) / 2 + (q - j - 1); v = fmaxf(C_up[pi * 32 + k], 0.f); }
        Cs[q][j][k] = v;
    }
    __syncthreads();

    if (t < 512) {
        int j = t & 15, k = t >> 4;
        float s1 = 0.f, s2 = 0.f;
        for (int q = 0; q < 16; ++q) {
            float c = Cs[q][j][k];
            s1 += hf[q] * c;
            s2 += hf[q] * c * c;
        }
        ws[WS_CCT  + k * 16 + j] = s1;
        ws[WS_CC2T + k * 16 + j] = s2;
    }
    {
        int k = t & 31, j = t >> 5;   // t in [0,512)
        float s = 0.f;
        for (int d = 0; d < D_; ++d) {
            float f = Ff[(j * D_ + d) * K_ + k];
            s += f * f;
        }
        ws[WS_F2 + j * K_ + k] = s;
    }
    for (int e = t; e < 8192; e += 512) {
        int j = e & 15, q = (e >> 4) & 15, k = e >> 8;
        ws[WS_CT + k * 256 + q * 16 + j] = Cs[q][j][k];
    }
}

__global__ __launch_bounds__(512, 2) void fgw_main(
    const float* __restrict__ adj, const float* __restrict__ features,
    const int* __restrict__ idxs, const float* __restrict__ Ff,
    const float* __restrict__ w1, const float* __restrict__ b1,
    const float* __restrict__ w2, const float* __restrict__ b2,
    const float* __restrict__ ws, float* __restrict__ out)
{
    __shared__ __align__(16) float xT[D_][20];        // xT[d][i]
    __shared__ float adj_s[NS_][17];
    __shared__ __align__(16) float M_all[K_][NS_][20]; // M_all[k][i][j]
    __shared__ __align__(16) float Twork[8][NS_][20];
    __shared__ __align__(16) float tmpw[8][NS_][20];
    __shared__ float pooled[D_];
    __shared__ float x2s[NS_], c1s[NS_], rss[NS_];
    __shared__ float alpha_s;
    __shared__ int   idx_s[NS_];

    const int b = blockIdx.x;
    const int t = threadIdx.x;

    if (t < NS_) idx_s[t] = idxs[b * NS_ + t];
    if (t < 256) adj_s[t >> 4][t & 15] = adj[b * 256 + t];
    __syncthreads();

    // Gather x (transposed) — idx == NV_ selects the appended zero row.
    for (int e = t; e < NS_ * D_; e += 512) {
        int i = e >> 7, d = e & 127;
        int ix = idx_s[i];
        xT[d][i] = (ix < NV_) ? features[ix * D_ + d] : 0.f;
    }
    __syncthreads();

    // Per-b stats: x2, adj rowsum/constC1, pooled.
    if (t < NS_) {
        float s = 0.f;
        for (int d = 0; d < D_; ++d) { float v = xT[d][t]; s += v * v; }
        x2s[t] = s;
    } else if (t >= 64 && t < 64 + NS_) {
        int i = t - 64;
        float s = 0.f, s2 = 0.f;
        for (int p = 0; p < NS_; ++p) { float a = adj_s[i][p]; s += a; s2 += a * a; }
        rss[i] = s;
        c1s[i] = s2 * (1.f / 16.f);
    } else if (t >= 128 && t < 256) {
        int d = t - 128;
        float s = 0.f;
        for (int i = 0; i < NS_; ++i) s += xT[d][i];
        pooled[d] = s * (1.f / 16.f);
    }
    __syncthreads();

    // alpha = sigmoid(relu(pooled@w1+b1)@w2+b2)
    if (t < 32) {
        float h = b1[t];
        for (int d = 0; d < D_; ++d) h = fmaf(pooled[d], w1[d * 32 + t], h);
        h = fmaxf(h, 0.f);
        float z = h * w2[t];
        #pragma unroll
        for (int s = 1; s < 32; s <<= 1) z += __shfl_xor(z, s);
        if (t == 0) alpha_s = 1.f / (1.f + __expf(-(z + b2[0])));
    }
    __syncthreads();

    // xf GEMM: out[i, c=(j*32+k)] = sum_d x[i,d]*F[j,d,k]; M = x2 + f2 - 2*xf
    {
        const int i0 = (t & 3) * 4;
        const int c0 = (t >> 2) * 4;
        const int jj = c0 >> 5;
        const int k0 = c0 & 31;
        float acc[4][4];
        #pragma unroll
        for (int a = 0; a < 4; ++a)
            #pragma unroll
            for (int c = 0; c < 4; ++c) acc[a][c] = 0.f;

        const float* Fp = Ff + jj * (D_ * K_) + k0;
        #pragma unroll 4
        for (int d = 0; d < D_; ++d) {
            float4 xv = *(const float4*)&xT[d][i0];
            float4 fv = *(const float4*)(Fp + d * K_);
            float xa[4] = {xv.x, xv.y, xv.z, xv.w};
            float fa[4] = {fv.x, fv.y, fv.z, fv.w};
            #pragma unroll
            for (int a = 0; a < 4; ++a)
                #pragma unroll
                for (int c = 0; c < 4; ++c)
                    acc[a][c] = fmaf(xa[a], fa[c], acc[a][c]);
        }
        float4 f2v = *(const float4*)(ws + WS_F2 + c0);
        float f2a[4] = {f2v.x, f2v.y, f2v.z, f2v.w};
        #pragma unroll
        for (int c = 0; c < 4; ++c) {
            int k = k0 + c;
            #pragma unroll
            for (int a = 0; a < 4; ++a)
                M_all[k][i0 + a][jj] = x2s[i0 + a] + f2a[c] - 2.f * acc[a][c];
        }
    }
    __syncthreads();

    // Per-(wave,k): cost -> sinkhorn -> T -> gw_tens(T) -> fgw
    const int w  = t >> 6;
    const int l  = t & 63;
    const int i  = l & 15;
    const int jr = l >> 4;
    const float alpha = alpha_s;
    const float oma   = 1.f - alpha;
    const float c1    = c1s[i];
    const float rs16  = rss[i] * (1.f / 16.f);
    const float lp    = -2.7725887222397811f;  // log(1/16)
    const float inv_eps = 1.f / EPS_;

    float lq_[4];
    #pragma unroll
    for (int r = 0; r < 4; ++r) lq_[r] = ws[WS_LHF + jr * 4 + r];

    for (int kk = 0; kk < 4; ++kk) {
        const int k = kk * 8 + w;

        float cctv[4], cc2v[4], Mv[4], cost[4];
        #pragma unroll
        for (int r = 0; r < 4; ++r) {
            int j = jr * 4 + r;
            cctv[r] = ws[WS_CCT  + k * 16 + j];
            cc2v[r] = ws[WS_CC2T + k * 16 + j];
        }
        {
            float4 m4 = *(const float4*)&M_all[k][i][jr * 4];
            Mv[0] = m4.x; Mv[1] = m4.y; Mv[2] = m4.z; Mv[3] = m4.w;
        }
        #pragma unroll
        for (int r = 0; r < 4; ++r)
            cost[r] = oma * Mv[r] + alpha * (c1 + cc2v[r] - 2.f * rs16 * cctv[r]);

        // log-domain sinkhorn, 2 iterations
        float f = 0.f, g[4] = {0.f, 0.f, 0.f, 0.f};
        #pragma unroll
        for (int it = 0; it < 2; ++it) {
            float a[4], m = -3.4e38f;
            #pragma unroll
            for (int r = 0; r < 4; ++r) { a[r] = (g[r] - cost[r]) * inv_eps; m = fmaxf(m, a[r]); }
            m = fmaxf(m, __shfl_xor(m, 16));
            m = fmaxf(m, __shfl_xor(m, 32));
            float s = 0.f;
            #pragma unroll
            for (int r = 0; r < 4; ++r) s += __expf(a[r] - m);
            s += __shfl_xor(s, 16);
            s += __shfl_xor(s, 32);
            f = EPS_ * (lp - (m + __logf(s)));

            #pragma unroll
            for (int r = 0; r < 4; ++r) {
                float bb = (f - cost[r]) * inv_eps;
                float mr = bb;
                #pragma unroll
                for (int sh = 1; sh < 16; sh <<= 1) mr = fmaxf(mr, __shfl_xor(mr, sh));
                float e = __expf(bb - mr);
                #pragma unroll
                for (int sh = 1; sh < 16; sh <<= 1) e += __shfl_xor(e, sh);
                g[r] = EPS_ * (lq_[r] - (mr + __logf(e)));
            }
        }

        float Tv[4];
        #pragma unroll
        for (int r = 0; r < 4; ++r) Tv[r] = __expf((f + g[r] - cost[r]) * inv_eps);

        // gw_tens(T): tmp = adj @ T ; cross = tmp @ C[:,:,k]
        #pragma unroll
        for (int r = 0; r < 4; ++r) Twork[w][i][jr * 4 + r] = Tv[r];
        __syncthreads();

        float tm[4] = {0.f, 0.f, 0.f, 0.f};
        for (int p = 0; p < 16; ++p) {
            float av = adj_s[i][p];
            float4 tv = *(const float4*)&Twork[w][p][jr * 4];
            tm[0] = fmaf(av, tv.x, tm[0]);
            tm[1] = fmaf(av, tv.y, tm[1]);
            tm[2] = fmaf(av, tv.z, tm[2]);
            tm[3] = fmaf(av, tv.w, tm[3]);
        }
        #pragma unroll
        for (int r = 0; r < 4; ++r) tmpw[w][i][jr * 4 + r] = tm[r];
        __syncthreads();

        float cr[4] = {0.f, 0.f, 0.f, 0.f};
        const float* Ctk = ws + WS_CT + k * 256;
        for (int q = 0; q < 16; ++q) {
            float tq = tmpw[w][i][q];
            float4 cv = *(const float4*)(Ctk + q * 16 + jr * 4);
            cr[0] = fmaf(tq, cv.x, cr[0]);
            cr[1] = fmaf(tq, cv.y, cr[1]);
            cr[2] = fmaf(tq, cv.z, cr[2]);
            cr[3] = fmaf(tq, cv.w, cr[3]);
        }

        float dot = 0.f;
        #pragma unroll
        for (int r = 0; r < 4; ++r) {
            float fin = oma * Mv[r] + alpha * (c1 + cc2v[r] - 2.f * cr[r]);
            dot += Tv[r] * fin;
        }
        #pragma unroll
        for (int sh = 1; sh < 64; sh <<= 1) dot += __shfl_xor(dot, sh);
        if (l == 0) out[b * K_ + k] = dot;
    }
}

extern "C" void kernel_launch(void* const* d_in, const int* in_sizes, int n_in,
                              void* d_out, int out_size, void* d_ws, size_t ws_size,
                              hipStream_t stream)
{
    (void)in_sizes; (void)n_in; (void)out_size; (void)ws_size;
    const float* adj      = (const float*)d_in[0];
    const float* features = (const float*)d_in[1];
    const int*   idxs     = (const int*)  d_in[2];
    const float* C_up     = (const float*)d_in[3];
    const float* Ff       = (const float*)d_in[4];
    const float* h_logits = (const float*)d_in[5];
    const float* w1       = (const float*)d_in[6];
    const float* b1       = (const float*)d_in[7];
    const float* w2       = (const float*)d_in[8];
    const float* b2       = (const float*)d_in[9];
    float* out = (float*)d_out;
    float* ws  = (float*)d_ws;

    hipLaunchKernelGGL(init_kernel, dim3(1), dim3(512), 0, stream, C_up, Ff, h_logits, ws);
    hipLaunchKernelGGL(fgw_main, dim3(B_), dim3(512), 0, stream,
                       adj, features, idxs, Ff, w1, b1, w2, b2, ws, out);
}

// Round 2
// 329.738 us; speedup vs baseline: 2.0060x; 2.0060x over previous
//
#include <hip/hip_runtime.h>

typedef unsigned short ushort;
typedef unsigned int uint;
typedef __attribute__((ext_vector_type(8))) short short8;
typedef __attribute__((ext_vector_type(4))) float f32x4;

#define B_    8192
#define NB_   2
#define GRID_ (B_ / NB_)
#define NS_   16
#define D_    128
#define K_    32
#define NV_   50000
#define SC_   28.853900817779268f   /* log2(e)/eps */
#define ISC_  0.03465735902799726f  /* eps*ln2     */

/* ws float offsets */
#define WS_HF    0
#define WS_LHF2  16
#define WS_CCT   32
#define WS_CC2T  544
#define WS_F2    1056
/* ws byte offsets */
#define WSB_FBHI 6272
#define WSB_FBLO 137344
#define WSB_CB1  268416
#define WSB_CB2  301184

__device__ __forceinline__ ushort bf16rne(float v) {
    uint u = __float_as_uint(v);
    uint r = (u + 0x7fffu + ((u >> 16) & 1u)) >> 16;
    return (ushort)r;
}
__device__ __forceinline__ float bf16tof(ushort h) { return __uint_as_float(((uint)h) << 16); }

template <int C>
__device__ __forceinline__ float dppmv(float x) {
    return __int_as_float(__builtin_amdgcn_update_dpp(
        __float_as_int(x), __float_as_int(x), C, 0xf, 0xf, false));
}
__device__ __forceinline__ float rowmax16(float x) {
    x = fmaxf(x, dppmv<0x121>(x));
    x = fmaxf(x, dppmv<0x122>(x));
    x = fmaxf(x, dppmv<0x124>(x));
    x = fmaxf(x, dppmv<0x128>(x));
    return x;
}
__device__ __forceinline__ float rowsum16(float x) {
    x += dppmv<0x121>(x);
    x += dppmv<0x122>(x);
    x += dppmv<0x124>(x);
    x += dppmv<0x128>(x);
    return x;
}
__device__ __forceinline__ short8 lo16x8(uint4 a, uint4 b) {
    union { short8 v; uint u[4]; } r;
    r.u[0] = __builtin_amdgcn_perm(a.y, a.x, 0x05040100u);
    r.u[1] = __builtin_amdgcn_perm(a.w, a.z, 0x05040100u);
    r.u[2] = __builtin_amdgcn_perm(b.y, b.x, 0x05040100u);
    r.u[3] = __builtin_amdgcn_perm(b.w, b.z, 0x05040100u);
    return r.v;
}
__device__ __forceinline__ short8 hi16x8(uint4 a, uint4 b) {
    union { short8 v; uint u[4]; } r;
    r.u[0] = __builtin_amdgcn_perm(a.y, a.x, 0x07060302u);
    r.u[1] = __builtin_amdgcn_perm(a.w, a.z, 0x07060302u);
    r.u[2] = __builtin_amdgcn_perm(b.y, b.x, 0x07060302u);
    r.u[3] = __builtin_amdgcn_perm(b.w, b.z, 0x07060302u);
    return r.v;
}
__device__ __forceinline__ f32x4 mfma16(short8 a, short8 b, f32x4 c) {
    return __builtin_amdgcn_mfma_f32_16x16x32_bf16(a, b, c, 0, 0, 0);
}

/* ---- init: F fragments (hi/lo split, B-frag order) ---- */
__global__ __launch_bounds__(512) void init_fb(const float* __restrict__ Ff, float* __restrict__ ws) {
    int idx = blockIdx.x * 512 + threadIdx.x;  /* [0, 65536) */
    int e = idx & 7, l = (idx >> 3) & 63, s = (idx >> 9) & 3, k = idx >> 11;
    int j = l & 15, kg = l >> 4;
    int d = s * 32 + kg * 8 + e;
    float v = Ff[(j * D_ + d) * K_ + k];
    ushort hb = bf16rne(v);
    ushort lb = bf16rne(v - bf16tof(hb));
    ushort* FBHI = (ushort*)((char*)ws + WSB_FBHI);
    ushort* FBLO = (ushort*)((char*)ws + WSB_FBLO);
    FBHI[idx] = hb;
    FBLO[idx] = lb;
}

/* ---- init: hf, cct, cc2t, f2, C fragments ---- */
__global__ __launch_bounds__(1024) void init_small(
    const float* __restrict__ C_up, const float* __restrict__ Ff,
    const float* __restrict__ h_logits, float* __restrict__ ws) {
    __shared__ float hf[16];
    __shared__ float Cs[16][16][32];
    __shared__ float f2p[16][32][2];
    const int t = threadIdx.x;

    if (t == 0) {
        float m = -3.4e38f;
        for (int p = 0; p < 16; ++p) m = fmaxf(m, h_logits[p]);
        float e[16], s = 0.f;
        for (int p = 0; p < 16; ++p) { e[p] = __expf(h_logits[p] - m); s += e[p]; }
        for (int p = 0; p < 16; ++p) {
            hf[p] = e[p] / s;
            ws[WS_HF + p] = hf[p];
            ws[WS_LHF2 + p] = log2f(hf[p]);
        }
    }
    for (int e0 = t; e0 < 16 * 16 * 32; e0 += 1024) {
        int k = e0 & 31, j = (e0 >> 5) & 15, q = e0 >> 9;
        float v = 0.f;
        if (q < j)      { int pi = q * (31 - q) / 2 + (j - q - 1); v = fmaxf(C_up[pi * 32 + k], 0.f); }
        else if (j < q) { int pi = j * (31 - j) / 2 + (q - j - 1); v = fmaxf(C_up[pi * 32 + k], 0.f); }
        Cs[q][j][k] = v;
    }
    __syncthreads();

    if (t < 512) {
        int k = t >> 4, j = t & 15;
        float s1 = 0.f, s2 = 0.f;
        for (int q = 0; q < 16; ++q) {
            float c = Cs[q][j][k];
            s1 += hf[q] * c;
            s2 += hf[q] * c * c;
        }
        ws[WS_CCT + k * 16 + j] = s1;
        ws[WS_CC2T + k * 16 + j] = s2;
    }
    {
        int k = t & 31, half = (t >> 5) & 1, j = t >> 6;
        float s = 0.f;
        for (int dd = 0; dd < 64; ++dd) {
            int d = half * 64 + dd;
            float f = Ff[(j * D_ + d) * K_ + k];
            s += f * f;
        }
        f2p[j][k][half] = s;
    }
    {
        ushort* CB1 = (ushort*)((char*)ws + WSB_CB1);
        ushort* CB2 = (ushort*)((char*)ws + WSB_CB2);
        for (int i0 = t; i0 < 16384; i0 += 1024) {
            int e = i0 & 7, l = (i0 >> 3) & 63, k = i0 >> 9;
            int kg = l >> 4, j = l & 15, q = (kg & 1) * 8 + e;
            float c = Cs[q][j][k];
            ushort hb = bf16rne(c);
            CB1[i0] = hb;
            CB2[i0] = (kg < 2) ? bf16rne(c - bf16tof(hb)) : (ushort)0;
        }
    }
    __syncthreads();
    if (t < 512) {
        int j = t >> 5, k = t & 31;
        ws[WS_F2 + j * 32 + k] = f2p[j][k][0] + f2p[j][k][1];
    }
}

/* ---- main ---- */
__global__ __launch_bounds__(512, 4) void fgw_main(
    const float* __restrict__ adj, const float* __restrict__ features,
    const int* __restrict__ idxs,
    const float* __restrict__ w1, const float* __restrict__ b1,
    const float* __restrict__ w2, const float* __restrict__ b2,
    const float* __restrict__ ws, float* __restrict__ out) {
    __shared__ __align__(16) ushort xA[NB_][2][4][64][8];   /* 16 KB */
    __shared__ __align__(16) uint  exch[8][2][16][20];      /* 20 KB (overlaid xT in setup) */
    __shared__ __align__(16) ushort adjA[NB_][64][8];       /* 2 KB  */
    __shared__ float adj_s[NB_][16][17];
    __shared__ float pooled[NB_][128];
    __shared__ float x2part[NB_][16][8];
    __shared__ float x2s[NB_][16], c1s[NB_][16], rss[NB_][16];
    __shared__ float alpha_sh[NB_];
    __shared__ int idx_sh[NB_][16];

    const int t = threadIdx.x;
    const int blk = blockIdx.x;
    float* xT = (float*)&exch[0][0][0][0];  /* [NB_][16][132] overlay */

    if (t < NB_ * 16) idx_sh[t >> 4][t & 15] = idxs[(blk * NB_ + (t >> 4)) * 16 + (t & 15)];
    {
        int pb = t >> 8, rem = t & 255;
        adj_s[pb][rem >> 4][rem & 15] = adj[(blk * NB_ + pb) * 256 + rem];
    }
    __syncthreads();

    if (t < 256) {
        int pb = t >> 7, i = (t >> 3) & 15, c = t & 7;
        int ix = idx_sh[pb][i];
        float vv[16];
        if (ix < NV_) {
            const float4* fp = (const float4*)(features + (size_t)ix * D_ + c * 16);
            float4 q0 = fp[0], q1 = fp[1], q2 = fp[2], q3 = fp[3];
            vv[0] = q0.x; vv[1] = q0.y; vv[2] = q0.z; vv[3] = q0.w;
            vv[4] = q1.x; vv[5] = q1.y; vv[6] = q1.z; vv[7] = q1.w;
            vv[8] = q2.x; vv[9] = q2.y; vv[10] = q2.z; vv[11] = q2.w;
            vv[12] = q3.x; vv[13] = q3.y; vv[14] = q3.z; vv[15] = q3.w;
        } else {
            #pragma unroll
            for (int e = 0; e < 16; ++e) vv[e] = 0.f;
        }
        float* xrow = xT + (pb * 16 + i) * 132 + c * 16;
        float s2 = 0.f;
        #pragma unroll
        for (int e = 0; e < 16; ++e) { xrow[e] = vv[e]; s2 += vv[e] * vv[e]; }
        x2part[pb][i][c] = s2;
        #pragma unroll
        for (int g = 0; g < 2; ++g) {
            int d0 = c * 16 + g * 8;
            int s = d0 >> 5, kg = (d0 >> 3) & 3;
            union { short8 v; ushort u[8]; } h8, l8;
            #pragma unroll
            for (int e = 0; e < 8; ++e) {
                float x = vv[g * 8 + e];
                ushort hb = bf16rne(x);
                h8.u[e] = hb;
                l8.u[e] = bf16rne(x - bf16tof(hb));
            }
            *(short8*)&xA[pb][0][s][kg * 16 + i][0] = h8.v;
            *(short8*)&xA[pb][1][s][kg * 16 + i][0] = l8.v;
        }
    } else if (t < 384) {
        int t2 = t - 256, pb = t2 >> 6, l = t2 & 63;
        int i = l & 15, kg = l >> 4;
        union { short8 v; ushort u[8]; } f8;
        #pragma unroll
        for (int e = 0; e < 8; ++e) {
            int p = (kg & 1) * 8 + e;
            float v = adj_s[pb][i][p];
            ushort hb = bf16rne(v);
            f8.u[e] = (kg < 2) ? hb : bf16rne(v - bf16tof(hb));
        }
        *(short8*)&adjA[pb][l][0] = f8.v;
    } else if (t < 416) {
        int t2 = t - 384, pb = t2 >> 4, i = t2 & 15;
        float s = 0.f, s2 = 0.f;
        for (int p = 0; p < 16; ++p) { float a = adj_s[pb][i][p]; s += a; s2 += a * a; }
        rss[pb][i] = s;
        c1s[pb][i] = s2 * (1.f / 16.f);
    }
    __syncthreads();

    if (t < NB_ * 128) {
        int pb = t >> 7, d = t & 127;
        float s = 0.f;
        for (int i = 0; i < 16; ++i) s += xT[(pb * 16 + i) * 132 + d];
        pooled[pb][d] = s * (1.f / 16.f);
    } else if (t < NB_ * 128 + NB_ * 16) {
        int t2 = t - NB_ * 128, pb = t2 >> 4, i = t2 & 15;
        float s = 0.f;
        #pragma unroll
        for (int c = 0; c < 8; ++c) s += x2part[pb][i][c];
        x2s[pb][i] = s;
    }
    __syncthreads();

    if (t < 64) {
        int pb = t >> 5, u = t & 31;
        float h = b1[u];
        for (int d = 0; d < D_; ++d) h = fmaf(pooled[pb][d], w1[d * 32 + u], h);
        h = fmaxf(h, 0.f);
        float z = h * w2[u];
        #pragma unroll
        for (int s = 1; s < 32; s <<= 1) z += __shfl_xor(z, s);
        if (u == 0) alpha_sh[pb] = 1.f / (1.f + __expf(-(z + b2[0])));
    }
    __syncthreads();

    /* ---- phase 1: xf via split-bf16 MFMA ---- */
    const int w = t >> 6, l = t & 63;
    const int jl = l & 15, ig = l >> 4;
    const ushort* FBHI = (const ushort*)((const char*)ws + WSB_FBHI);
    const ushort* FBLO = (const ushort*)((const char*)ws + WSB_FBLO);

    f32x4 acc[NB_][4];
    #pragma unroll
    for (int pb = 0; pb < NB_; ++pb)
        #pragma unroll
        for (int kk = 0; kk < 4; ++kk) acc[pb][kk] = (f32x4){0.f, 0.f, 0.f, 0.f};

    #pragma unroll
    for (int s = 0; s < 4; ++s) {
        short8 Ah[NB_], Al[NB_];
        #pragma unroll
        for (int pb = 0; pb < NB_; ++pb) {
            Ah[pb] = *(const short8*)&xA[pb][0][s][l][0];
            Al[pb] = *(const short8*)&xA[pb][1][s][l][0];
        }
        #pragma unroll
        for (int kk = 0; kk < 4; ++kk) {
            int k = kk * 8 + w;
            const short8 Bh = *(const short8*)(FBHI + ((k * 4 + s) * 64 + l) * 8);
            const short8 Bl = *(const short8*)(FBLO + ((k * 4 + s) * 64 + l) * 8);
            #pragma unroll
            for (int pb = 0; pb < NB_; ++pb) {
                acc[pb][kk] = mfma16(Ah[pb], Bh, acc[pb][kk]);
                acc[pb][kk] = mfma16(Al[pb], Bh, acc[pb][kk]);
                acc[pb][kk] = mfma16(Ah[pb], Bl, acc[pb][kk]);
            }
        }
    }

    /* ---- phase 2: per-(b,k) sinkhorn + gw_tens + fgw ---- */
    const float lq2 = ws[WS_LHF2 + jl];
    uint* Tb = &exch[w][0][0][0];
    uint* Mb = &exch[w][1][0][0];
    const ushort* CB1 = (const ushort*)((const char*)ws + WSB_CB1);
    const ushort* CB2 = (const ushort*)((const char*)ws + WSB_CB2);
    const short8 z8 = {0, 0, 0, 0, 0, 0, 0, 0};

    #pragma unroll
    for (int pb = 0; pb < NB_; ++pb) {
        const float alpha = alpha_sh[pb], oma = 1.f - alpha;
        float x2r[4], c1r[4], rsr[4];
        #pragma unroll
        for (int r = 0; r < 4; ++r) {
            x2r[r] = x2s[pb][ig * 4 + r];
            c1r[r] = c1s[pb][ig * 4 + r];
            rsr[r] = rss[pb][ig * 4 + r] * (1.f / 16.f);
        }
        const short8 Aadj = *(const short8*)&adjA[pb][l][0];

        #pragma unroll
        for (int kk = 0; kk < 4; ++kk) {
            const int k = kk * 8 + w;
            const float f2v = ws[WS_F2 + jl * 32 + k];
            const float cctv = ws[WS_CCT + k * 16 + jl];
            const float cc2v = ws[WS_CC2T + k * 16 + jl];
            float Chat[4];
            #pragma unroll
            for (int r = 0; r < 4; ++r) {
                float M = x2r[r] + f2v - 2.f * acc[pb][kk][r];
                float gw0 = c1r[r] + cc2v - 2.f * rsr[r] * cctv;
                Chat[r] = SC_ * (oma * M + alpha * gw0);
            }
            /* log2-domain sinkhorn, 2 iters; h_sub=1/16 -> lp2=-4 */
            float G = 0.f, Fh[4];
            #pragma unroll
            for (int it = 0; it < 2; ++it) {
                #pragma unroll
                for (int r = 0; r < 4; ++r) {
                    float a = G - Chat[r];
                    float m = rowmax16(a);
                    float e = exp2f(a - m);
                    float S = rowsum16(e);
                    Fh[r] = -4.f - m - log2f(S);
                }
                float m2 = fmaxf(fmaxf(Fh[0] - Chat[0], Fh[1] - Chat[1]),
                                 fmaxf(Fh[2] - Chat[2], Fh[3] - Chat[3]));
                m2 = fmaxf(m2, __shfl_xor(m2, 16));
                m2 = fmaxf(m2, __shfl_xor(m2, 32));
                float S2 = 0.f;
                #pragma unroll
                for (int r = 0; r < 4; ++r) S2 += exp2f(Fh[r] - Chat[r] - m2);
                S2 += __shfl_xor(S2, 16);
                S2 += __shfl_xor(S2, 32);
                G = lq2 - m2 - log2f(S2);
            }
            float Tv[4];
            #pragma unroll
            for (int r = 0; r < 4; ++r) Tv[r] = exp2f(Fh[r] + G - Chat[r]);

            /* gw_tens(T) via split-bf16 MFMA:
               tmp = adj @ T ; cross = tmp @ C[:,:,k] */
            uint4 pk;
            {
                uint pw[4];
                #pragma unroll
                for (int r = 0; r < 4; ++r) {
                    ushort th = bf16rne(Tv[r]);
                    float tlf = Tv[r] - bf16tof(th);
                    pw[r] = (uint)th | ((uint)bf16rne(tlf) << 16);
                }
                pk.x = pw[0]; pk.y = pw[1]; pk.z = pw[2]; pk.w = pw[3];
            }
            *(uint4*)&Tb[jl * 20 + ig * 4] = pk;
            uint4 tw = *(const uint4*)&Tb[jl * 20 + (ig & 1) * 8];
            uint4 tw2 = *(const uint4*)&Tb[jl * 20 + (ig & 1) * 8 + 4];
            short8 Bt1 = lo16x8(tw, tw2);
            short8 Bt2 = (ig < 2) ? hi16x8(tw, tw2) : z8;
            f32x4 tmp = {0.f, 0.f, 0.f, 0.f};
            tmp = mfma16(Aadj, Bt1, tmp);
            tmp = mfma16(Aadj, Bt2, tmp);

            #pragma unroll
            for (int r = 0; r < 4; ++r) {
                ushort th = bf16rne(tmp[r]);
                float tlf = tmp[r] - bf16tof(th);
                Mb[(ig * 4 + r) * 20 + jl] = (uint)th | ((uint)bf16rne(tlf) << 16);
            }
            uint4 aw = *(const uint4*)&Mb[jl * 20 + (ig & 1) * 8];
            uint4 aw2 = *(const uint4*)&Mb[jl * 20 + (ig & 1) * 8 + 4];
            short8 Atm = (ig < 2) ? lo16x8(aw, aw2) : hi16x8(aw, aw2);
            const short8 C1f = *(const short8*)(CB1 + (k * 64 + l) * 8);
            const short8 C2f = *(const short8*)(CB2 + (k * 64 + l) * 8);
            f32x4 cr = {0.f, 0.f, 0.f, 0.f};
            cr = mfma16(Atm, C1f, cr);
            cr = mfma16(Atm, C2f, cr);

            float dot = 0.f;
            #pragma unroll
            for (int r = 0; r < 4; ++r) {
                float fc = Chat[r] * ISC_ + 2.f * alpha * (rsr[r] * cctv - cr[r]);
                dot = fmaf(Tv[r], fc, dot);
            }
            dot = rowsum16(dot);
            dot += __shfl_xor(dot, 16);
            dot += __shfl_xor(dot, 32);
            if (l == 0) out[(blk * NB_ + pb) * K_ + k] = dot;
        }
    }
}

extern "C" void kernel_launch(void* const* d_in, const int* in_sizes, int n_in,
                              void* d_out, int out_size, void* d_ws, size_t ws_size,
                              hipStream_t stream) {
    (void)in_sizes; (void)n_in; (void)out_size; (void)ws_size;
    const float* adj      = (const float*)d_in[0];
    const float* features = (const float*)d_in[1];
    const int*   idxs     = (const int*)  d_in[2];
    const float* C_up     = (const float*)d_in[3];
    const float* Ff       = (const float*)d_in[4];
    const float* h_logits = (const float*)d_in[5];
    const float* w1       = (const float*)d_in[6];
    const float* b1       = (const float*)d_in[7];
    const float* w2       = (const float*)d_in[8];
    const float* b2       = (const float*)d_in[9];
    float* out = (float*)d_out;
    float* ws  = (float*)d_ws;

    hipLaunchKernelGGL(init_fb, dim3(128), dim3(512), 0, stream, Ff, ws);
    hipLaunchKernelGGL(init_small, dim3(1), dim3(1024), 0, stream, C_up, Ff, h_logits, ws);
    hipLaunchKernelGGL(fgw_main, dim3(GRID_), dim3(512), 0, stream,
                       adj, features, idxs, w1, b1, w2, b2, ws, out);
}